// Round 2
// baseline (1429.503 us; speedup 1.0000x reference)
//
#include <hip/hip_runtime.h>
#include <hip/hip_bf16.h>

typedef __hip_bfloat16 bf16;

#define F_DIM 64
#define ATOMS_PER_BLOCK 32
#define ATOMS_PER_WAVE 8

__device__ __forceinline__ float b2f(bf16 v) { return __bfloat162float(v); }
__device__ __forceinline__ bf16  f2b(float v) { return __float2bfloat16(v); }

// Load element i of a float tensor whose storage dtype is fp32 (F32=true) or bf16.
template <bool F32>
__device__ __forceinline__ float ldf(const void* p, size_t i) {
    if (F32) return ((const float*)p)[i];
    return b2f(((const bf16*)p)[i]);
}

// ---------------------------------------------------------------------------
// Kernel 0: dtype detection.
//  flags[0] = 1 if float tensors are stored fp32, 0 if bf16
//  flags[1] = 1 if index tensors are stored int64, 0 if int32
// Heuristic: bf16 view of fp32 data has uniform-random exponents in its
// low-half words (~8% "sane"); real bf16 N(0,1) data is ~100% sane.
// int64 indices (< 25000) have all-zero high words.
// ---------------------------------------------------------------------------
__global__ void detect_kernel(const void* emb, const void* idxi, int* flags)
{
    if (threadIdx.x == 0 && blockIdx.x == 0) {
        const unsigned short* u = (const unsigned short*)emb;
        int sane = 0;
        for (int k = 0; k < 128; k++) {
            unsigned short b = u[2 * k];
            unsigned e = (b >> 7) & 0xFF;
            if ((b & 0x7FFF) == 0 || (e >= 117 && e <= 137)) sane++;
        }
        const unsigned* w = (const unsigned*)idxi;
        int zhi = 0;
        for (int k = 0; k < 128; k++)
            if (w[2 * k + 1] == 0u) zhi++;
        flags[0] = (sane < 64) ? 1 : 0;   // not sane as bf16 -> fp32 storage
        flags[1] = (zhi >= 64) ? 1 : 0;   // high words all zero -> int64
    }
}

// ---------------------------------------------------------------------------
// Kernel 1: per-atom MLP  x = (silu(emb@W1 + b1)) @ W2 + b2   -> ws (fp32)
// One wave handles 8 atoms; weights read from global (L1/L2 resident).
// ---------------------------------------------------------------------------
template <bool F32>
__global__ __launch_bounds__(256) void atom_transform_kernel(
    const int* __restrict__ flags,
    const void* __restrict__ emb, const void* __restrict__ W1,
    const void* __restrict__ b1, const void* __restrict__ W2,
    const void* __restrict__ b2, float* __restrict__ x, int n_atoms)
{
    if ((flags[0] != 0) != F32) return;

    __shared__ float semb[ATOMS_PER_BLOCK][F_DIM];  // 8 KB
    __shared__ float sh[ATOMS_PER_BLOCK][F_DIM];    // 8 KB

    int t = threadIdx.x;
    int atom0 = blockIdx.x * ATOMS_PER_BLOCK;
    for (int i = t; i < ATOMS_PER_BLOCK * F_DIM; i += 256) {
        int a = atom0 + (i >> 6);
        semb[i >> 6][i & 63] = (a < n_atoms) ? ldf<F32>(emb, (size_t)a * F_DIM + (i & 63)) : 0.f;
    }
    __syncthreads();

    int wave = t >> 6, lane = t & 63;
    int ab = wave * ATOMS_PER_WAVE;

    // h = silu(emb @ W1 + b1) ; lane owns output feature g = lane
    float acc1[ATOMS_PER_WAVE];
    #pragma unroll
    for (int a = 0; a < ATOMS_PER_WAVE; a++) acc1[a] = ldf<F32>(b1, lane);
    for (int f = 0; f < F_DIM; f++) {
        float w = ldf<F32>(W1, (size_t)f * 64 + lane);
        #pragma unroll
        for (int a = 0; a < ATOMS_PER_WAVE; a++) acc1[a] += semb[ab + a][f] * w;
    }
    #pragma unroll
    for (int a = 0; a < ATOMS_PER_WAVE; a++) {
        float v = acc1[a];
        sh[ab + a][lane] = v / (1.f + __expf(-v));   // silu
    }
    // each wave only reads its own rows of sh -> no barrier needed

    // x = h @ W2 + b2 ; lane owns outputs lane, lane+64, lane+128
    float a0[ATOMS_PER_WAVE], a1[ATOMS_PER_WAVE], a2[ATOMS_PER_WAVE];
    #pragma unroll
    for (int a = 0; a < ATOMS_PER_WAVE; a++) {
        a0[a] = ldf<F32>(b2, lane);
        a1[a] = ldf<F32>(b2, 64 + lane);
        a2[a] = ldf<F32>(b2, 128 + lane);
    }
    for (int g = 0; g < F_DIM; g++) {
        float w0 = ldf<F32>(W2, (size_t)g * 192 + lane);
        float w1 = ldf<F32>(W2, (size_t)g * 192 + 64 + lane);
        float w2 = ldf<F32>(W2, (size_t)g * 192 + 128 + lane);
        #pragma unroll
        for (int a = 0; a < ATOMS_PER_WAVE; a++) {
            float hg = sh[ab + a][g];
            a0[a] += hg * w0; a1[a] += hg * w1; a2[a] += hg * w2;
        }
    }
    #pragma unroll
    for (int a = 0; a < ATOMS_PER_WAVE; a++) {
        int atom = atom0 + ab + a;
        if (atom < n_atoms) {
            size_t base = (size_t)atom * 192;
            x[base + lane]       = a0[a];
            x[base + 64 + lane]  = a1[a];
            x[base + 128 + lane] = a2[a];
        }
    }
}

// ---------------------------------------------------------------------------
// Kernel 2: zero the fp32 accumulators (ws is poisoned 0xAA before each call)
// ---------------------------------------------------------------------------
__global__ void zero_kernel(float4* __restrict__ p, size_t n4)
{
    size_t stride = (size_t)gridDim.x * blockDim.x;
    for (size_t k = (size_t)blockIdx.x * blockDim.x + threadIdx.x; k < n4; k += stride)
        p[k] = make_float4(0.f, 0.f, 0.f, 0.f);
}

// ---------------------------------------------------------------------------
// Kernel 3: per-pair modulation + scatter-add (fp32 atomics into ws)
// One wave per 2 pairs; lane = feature. Lane loads are coalesced.
// ---------------------------------------------------------------------------
template <bool F32, bool IDX64>
__global__ __launch_bounds__(256) void pair_kernel(
    const int* __restrict__ flags,
    const void* __restrict__ Wij, const void* __restrict__ dir_ij,
    const void* __restrict__ idx_i, const void* __restrict__ idx_j,
    const float* __restrict__ x, const void* __restrict__ mu,
    float* __restrict__ accq, float* __restrict__ accmu, int n_pairs)
{
    if ((flags[0] != 0) != F32) return;
    if ((flags[1] != 0) != IDX64) return;

    int wave = threadIdx.x >> 6, lane = threadIdx.x & 63;
    int ebase = (blockIdx.x * 4 + wave) * 2;

    for (int e = ebase; e < ebase + 2; e++) {
        if (e >= n_pairs) break;
        int i = IDX64 ? (int)((const long long*)idx_i)[e] : ((const int*)idx_i)[e];
        int j = IDX64 ? (int)((const long long*)idx_j)[e] : ((const int*)idx_j)[e];

        float w0 = ldf<F32>(Wij, (size_t)e * 192 + lane);
        float w1 = ldf<F32>(Wij, (size_t)e * 192 + 64 + lane);
        float w2 = ldf<F32>(Wij, (size_t)e * 192 + 128 + lane);

        const float* xp = x + (size_t)j * 192;
        float dq    = w0 * xp[lane];
        float dmuR  = w1 * xp[64 + lane];
        float dmumu = w2 * xp[128 + lane];

        float d0 = ldf<F32>(dir_ij, (size_t)e * 3 + 0);
        float d1 = ldf<F32>(dir_ij, (size_t)e * 3 + 1);
        float d2 = ldf<F32>(dir_ij, (size_t)e * 3 + 2);

        float m0 = ldf<F32>(mu, (size_t)j * 192 + lane);
        float m1 = ldf<F32>(mu, (size_t)j * 192 + 64 + lane);
        float m2 = ldf<F32>(mu, (size_t)j * 192 + 128 + lane);

        unsafeAtomicAdd(&accq[(size_t)i * 64 + lane], dq);
        float* am = accmu + (size_t)i * 192;
        unsafeAtomicAdd(&am[lane],       dmuR * d0 + dmumu * m0);
        unsafeAtomicAdd(&am[64 + lane],  dmuR * d1 + dmumu * m1);
        unsafeAtomicAdd(&am[128 + lane], dmuR * d2 + dmumu * m2);
    }
}

// ---------------------------------------------------------------------------
// Kernel 4: finalize  out = base + acc  (output dtype == input storage dtype)
// ---------------------------------------------------------------------------
template <bool F32>
__global__ void finalize_kernel(
    const int* __restrict__ flags,
    const void* __restrict__ emb, const void* __restrict__ mu,
    const float* __restrict__ accq, const float* __restrict__ accmu,
    void* __restrict__ out, int n_atoms)
{
    if ((flags[0] != 0) != F32) return;
    size_t stride = (size_t)gridDim.x * blockDim.x;
    size_t nq = (size_t)n_atoms * 64;
    size_t nm = (size_t)n_atoms * 192;
    for (size_t k = (size_t)blockIdx.x * blockDim.x + threadIdx.x; k < nq; k += stride) {
        float v = ldf<F32>(emb, k) + accq[k];
        if (F32) ((float*)out)[k] = v; else ((bf16*)out)[k] = f2b(v);
    }
    for (size_t k = (size_t)blockIdx.x * blockDim.x + threadIdx.x; k < nm; k += stride) {
        float v = ldf<F32>(mu, k) + accmu[k];
        if (F32) ((float*)out)[nq + k] = v; else ((bf16*)out)[nq + k] = f2b(v);
    }
}

// ---------------------------------------------------------------------------
extern "C" void kernel_launch(void* const* d_in, const int* in_sizes, int n_in,
                              void* d_out, int out_size, void* d_ws, size_t ws_size,
                              hipStream_t stream)
{
    const void* emb   = d_in[0];
    const void* mu    = d_in[1];
    const void* Wij   = d_in[2];
    const void* dirij = d_in[3];
    const void* idx_i = d_in[4];
    const void* idx_j = d_in[5];
    const void* W1    = d_in[6];
    const void* b1    = d_in[7];
    const void* W2    = d_in[8];
    const void* b2    = d_in[9];

    int n_atoms = in_sizes[0] / 64;     // (N,1,64)
    int n_pairs = in_sizes[2] / 192;    // (E,1,192)

    // Workspace layout:
    //   flags : 2 ints (detection results), 256B slot
    //   x     : n_atoms*192 f32   (atom MLP output)
    //   accq  : n_atoms*64  f32
    //   accmu : n_atoms*192 f32   (contiguous after accq)
    char* ws = (char*)d_ws;
    int*   flags = (int*)ws;
    float* x     = (float*)(ws + 256);
    float* accq  = x + (size_t)n_atoms * 192;
    float* accmu = accq + (size_t)n_atoms * 64;

    detect_kernel<<<1, 64, 0, stream>>>(emb, idx_i, flags);

    atom_transform_kernel<true ><<<(n_atoms + 31) / 32, 256, 0, stream>>>(flags, emb, W1, b1, W2, b2, x, n_atoms);
    atom_transform_kernel<false><<<(n_atoms + 31) / 32, 256, 0, stream>>>(flags, emb, W1, b1, W2, b2, x, n_atoms);

    size_t n4 = (size_t)n_atoms * 256 / 4;   // accq+accmu floats / 4
    zero_kernel<<<1024, 256, 0, stream>>>((float4*)accq, n4);

    int pair_grid = (n_pairs + 7) / 8;       // 4 waves/block, 2 pairs/wave
    pair_kernel<true,  false><<<pair_grid, 256, 0, stream>>>(flags, Wij, dirij, idx_i, idx_j, x, mu, accq, accmu, n_pairs);
    pair_kernel<true,  true ><<<pair_grid, 256, 0, stream>>>(flags, Wij, dirij, idx_i, idx_j, x, mu, accq, accmu, n_pairs);
    pair_kernel<false, false><<<pair_grid, 256, 0, stream>>>(flags, Wij, dirij, idx_i, idx_j, x, mu, accq, accmu, n_pairs);
    pair_kernel<false, true ><<<pair_grid, 256, 0, stream>>>(flags, Wij, dirij, idx_i, idx_j, x, mu, accq, accmu, n_pairs);

    finalize_kernel<true ><<<2048, 256, 0, stream>>>(flags, emb, mu, accq, accmu, d_out, n_atoms);
    finalize_kernel<false><<<2048, 256, 0, stream>>>(flags, emb, mu, accq, accmu, d_out, n_atoms);
}